// Round 9
// baseline (20258.263 us; speedup 1.0000x reference)
//
#include <hip/hip_runtime.h>
#include <math.h>

#define BATCH 128
#define SEQ   512
#define IN    128
#define HID   256
#define G4    1024   // 4*HID
#define OUT   128

// ---------------- fallback: zero d_out (clean validation-failure signal) ----------------
__global__ __launch_bounds__(256) void zero_out_kernel(float* __restrict__ out, int n) {
    int i = blockIdx.x * 256 + threadIdx.x;
    if (i < n) out[i] = 0.0f;
}

// ---------------- MONOLITHIC diagnostic: entire model in one kernel ----------------
// One block per batch row (128 blocks x 256 threads). No workspace, no weight
// transposes, no staged xg: every value computed directly from the raw inputs
// exactly as the reference equations read. Thread j owns hidden unit j.
__global__ __launch_bounds__(256) void lstm_mono(
    const float* __restrict__ x,   const float* __restrict__ Wih,
    const float* __restrict__ Whh, const float* __restrict__ bih,
    const float* __restrict__ bhh, const float* __restrict__ fcW,
    const float* __restrict__ fcb, float* __restrict__ out)
{
    __shared__ __align__(16) float xs[IN];     // current x[b,t,:]
    __shared__ __align__(16) float h[HID];     // h_{t}
    const int b = blockIdx.x;      // 0..127
    const int j = threadIdx.x;     // 0..255

    float c = 0.0f;
    h[j] = 0.0f;
    __syncthreads();

    // fused biases for this unit's 4 gates (PyTorch stacking order i,f,g,o)
    const float bi = bih[0 * HID + j] + bhh[0 * HID + j];
    const float bf = bih[1 * HID + j] + bhh[1 * HID + j];
    const float bg = bih[2 * HID + j] + bhh[2 * HID + j];
    const float bo = bih[3 * HID + j] + bhh[3 * HID + j];

    // weight rows for this unit (original layouts: Wih [4H][I], Whh [4H][H])
    const float* wih_i = Wih + (size_t)(0 * HID + j) * IN;
    const float* wih_f = Wih + (size_t)(1 * HID + j) * IN;
    const float* wih_g = Wih + (size_t)(2 * HID + j) * IN;
    const float* wih_o = Wih + (size_t)(3 * HID + j) * IN;
    const float* whh_i = Whh + (size_t)(0 * HID + j) * HID;
    const float* whh_f = Whh + (size_t)(1 * HID + j) * HID;
    const float* whh_g = Whh + (size_t)(2 * HID + j) * HID;
    const float* whh_o = Whh + (size_t)(3 * HID + j) * HID;

    const float* xrow = x + (size_t)b * SEQ * IN;
    float*       orow = out + (size_t)b * SEQ * OUT;

    for (int t = 0; t < SEQ; ++t) {
        if (j < IN) xs[j] = xrow[(size_t)t * IN + j];
        __syncthreads();                         // xs ready

        float ai = bi, af = bf, ag = bg, ao = bo;

        // input contribution: sum_i x[b,t,i] * Wih[gate_row][i]
        for (int i = 0; i < IN; i += 4) {
            const float4 xv = *(const float4*)&xs[i];
            const float4 wi = *(const float4*)&wih_i[i];
            const float4 wf = *(const float4*)&wih_f[i];
            const float4 wg = *(const float4*)&wih_g[i];
            const float4 wo = *(const float4*)&wih_o[i];
            ai += xv.x * wi.x + xv.y * wi.y + xv.z * wi.z + xv.w * wi.w;
            af += xv.x * wf.x + xv.y * wf.y + xv.z * wf.z + xv.w * wf.w;
            ag += xv.x * wg.x + xv.y * wg.y + xv.z * wg.z + xv.w * wg.w;
            ao += xv.x * wo.x + xv.y * wo.y + xv.z * wo.z + xv.w * wo.w;
        }
        // recurrent contribution: sum_k h[k] * Whh[gate_row][k]
        for (int k = 0; k < HID; k += 4) {
            const float4 hv = *(const float4*)&h[k];
            const float4 wi = *(const float4*)&whh_i[k];
            const float4 wf = *(const float4*)&whh_f[k];
            const float4 wg = *(const float4*)&whh_g[k];
            const float4 wo = *(const float4*)&whh_o[k];
            ai += hv.x * wi.x + hv.y * wi.y + hv.z * wi.z + hv.w * wi.w;
            af += hv.x * wf.x + hv.y * wf.y + hv.z * wf.z + hv.w * wf.w;
            ag += hv.x * wg.x + hv.y * wg.y + hv.z * wg.z + hv.w * wg.w;
            ao += hv.x * wo.x + hv.y * wo.y + hv.z * wo.z + hv.w * wo.w;
        }
        __syncthreads();                         // all reads of h_t done

        const float is = 1.0f / (1.0f + expf(-ai));
        const float fs = 1.0f / (1.0f + expf(-af));
        const float gt = tanhf(ag);
        const float os = 1.0f / (1.0f + expf(-ao));
        c = fs * c + is * gt;
        const float ht = os * tanhf(c);

        h[j] = ht;
        __syncthreads();                         // h_{t+1} ready

        // fused fc: out[b,t,o] = sum_k h[k] * fcW[o][k] + fcb[o]
        if (j < OUT) {
            const float* wf = fcW + (size_t)j * HID;
            float acc = fcb[j];
            for (int k = 0; k < HID; k += 4) {
                const float4 hv = *(const float4*)&h[k];
                const float4 wv = *(const float4*)&wf[k];
                acc += hv.x * wv.x + hv.y * wv.y + hv.z * wv.z + hv.w * wv.w;
            }
            orow[(size_t)t * OUT + j] = acc;
        }
        // next iteration's xs write is safe: fc reads only h/fcW, and the
        // gate phase reads xs only after the top-of-loop barrier.
    }
}

// ---------------- launch ----------------
extern "C" void kernel_launch(void* const* d_in, const int* in_sizes, int n_in,
                              void* d_out, int out_size, void* d_ws, size_t ws_size,
                              hipStream_t stream)
{
    float* out = (float*)d_out;

    // ---- STRICT size-based input identification (element counts; verified in
    // rounds 6-8: a miss would produce err=absmax_ref~1.97, we observed 0.385).
    const float* x   = nullptr;
    const float* Wih = nullptr;
    const float* Whh = nullptr;
    const float* bih = nullptr;
    const float* bhh = nullptr;
    const float* fcW = nullptr;
    const float* fcb = nullptr;
    for (int i = 0; i < n_in; ++i) {
        const float* p = (const float*)d_in[i];
        switch (in_sizes[i]) {
            case 8388608: x   = p; break;   // 128*512*128
            case 131072:  Wih = p; break;   // 1024*128
            case 262144:  Whh = p; break;   // 1024*256
            case 32768:   fcW = p; break;   // 128*256
            case 128:     fcb = p; break;
            case 1024:    if (!bih) bih = p; else bhh = p; break;  // order-free (summed)
            default: break;
        }
    }
    if (!x || !Wih || !Whh || !bih || !bhh || !fcW || !fcb) {
        zero_out_kernel<<<(out_size + 255) / 256, 256, 0, stream>>>(out, out_size);
        return;
    }

    // Single monolithic kernel; d_ws intentionally untouched.
    lstm_mono<<<BATCH, 256, 0, stream>>>(x, Wih, Whh, bih, bhh, fcW, fcb, out);
}